// Round 10
// baseline (237.761 us; speedup 1.0000x reference)
//
#include <hip/hip_runtime.h>
#include <hip/hip_bf16.h>

#define DIM    1024
#define NH     16
#define DH     64
#define NSEQ   1605
#define HWIN   1600
#define PREFIX 5
#define NSEQP  1664   // 26*64, padded M / padded seq
#define KX     3072   // extended K': split-3 as [hi | lo*Bh | hi*Bl] segments

typedef __bf16 bf16_t;
typedef bf16_t bf16x4 __attribute__((ext_vector_type(4)));
typedef bf16_t bf16x8 __attribute__((ext_vector_type(8)));
typedef float  f32x4  __attribute__((ext_vector_type(4)));
typedef unsigned short u16;

#define MFMA(a,b,c) __builtin_amdgcn_mfma_f32_16x16x32_bf16(a,b,c,0,0,0)

union BU { bf16_t b; u16 u; };

// ---------------------------------------------------------------------------
// global->LDS staging of [ROWS][64-half] tile: linear LDS dest, XOR chunk
// swizzle applied to the GLOBAL source, swizzled read via frag() below.
// ---------------------------------------------------------------------------
template<int ROWS>
__device__ __forceinline__ void stage64(const bf16_t* __restrict__ seg,
                                        int row0, int ldk, int kin,
                                        bf16_t* lds, int tid)
{
    const int l = tid & 63, w = tid >> 6;
#pragma unroll
    for (int i = 0; i < ROWS / 32; ++i) {
        const int rb = i * 32 + w * 8;            // wave-uniform LDS row base
        const int r  = rb + (l >> 3);             // lane's tile row
        const int p  = l & 7;                     // physical 16B chunk
        const bf16_t* src = seg + (size_t)(row0 + r) * ldk + kin + ((p ^ (r & 7)) << 3);
        __builtin_amdgcn_global_load_lds(
            (const __attribute__((address_space(1))) void*)src,
            (__attribute__((address_space(3))) void*)(lds + rb * 64),
            16, 0, 0);
    }
}

__device__ __forceinline__ bf16x8 frag(const bf16_t* lds, int row, int ch) {
    return *(const bf16x8*)&lds[row * 64 + ((ch ^ (row & 7)) << 3)];
}

// ---------------------------------------------------------------------------
// prep: split fp32 inputs into hi/lo bf16 planes.
// ---------------------------------------------------------------------------
#define NX4 (NSEQP * 256)
#define NQ4 (3072 * 256)
#define NP4 (1024 * 256)

__global__ __launch_bounds__(256) void prep_kernel(
    const float* __restrict__ x, const float* __restrict__ Wq,
    const float* __restrict__ Wp,
    bf16_t* __restrict__ xh, bf16_t* __restrict__ xl,
    bf16_t* __restrict__ wqh, bf16_t* __restrict__ wql,
    bf16_t* __restrict__ wph, bf16_t* __restrict__ wpl)
{
    const int i = blockIdx.x * 256 + threadIdx.x;
    if (i >= NX4 + NQ4 + NP4) return;
    float4 v = make_float4(0.f, 0.f, 0.f, 0.f);
    bf16_t *ph, *pl;
    size_t off;
    if (i < NX4) {
        if ((i >> 8) < NSEQ) v = ((const float4*)x)[i];
        ph = xh; pl = xl; off = (size_t)i * 4;
    } else if (i < NX4 + NQ4) {
        int j = i - NX4;
        v = ((const float4*)Wq)[j];
        ph = wqh; pl = wql; off = (size_t)j * 4;
    } else {
        int j = i - NX4 - NQ4;
        v = ((const float4*)Wp)[j];
        ph = wph; pl = wpl; off = (size_t)j * 4;
    }
    bf16_t h0 = (bf16_t)v.x, h1 = (bf16_t)v.y, h2 = (bf16_t)v.z, h3 = (bf16_t)v.w;
    bf16x4 hv = {h0, h1, h2, h3};
    bf16x4 lv = {(bf16_t)(v.x - (float)h0), (bf16_t)(v.y - (float)h1),
                 (bf16_t)(v.z - (float)h2), (bf16_t)(v.w - (float)h3)};
    *(bf16x4*)(ph + off) = hv;
    *(bf16x4*)(pl + off) = lv;
}

// ---------------------------------------------------------------------------
// GEMM 1: qkv = x @ W_qkv^T, plain bf16 GEMM over K'=3072.
// 64x128 tile, BK=64, 4 waves (2x2 of 32x64), 2-phase double-buffered LDS.
// Grid 24x26 = 624; XCD column-band swizzle. RoPE/split/V^T fused epilogue.
// ---------------------------------------------------------------------------
__global__ __launch_bounds__(256, 2) void gemm_qkv(
    const bf16_t* __restrict__ xh, const bf16_t* __restrict__ xl,
    const bf16_t* __restrict__ wqh, const bf16_t* __restrict__ wql,
    const float* __restrict__ rope,
    bf16_t* __restrict__ Qhi, bf16_t* __restrict__ Qlo,
    bf16_t* __restrict__ Khi, bf16_t* __restrict__ Klo,
    bf16_t* __restrict__ Vt)
{
    __shared__ bf16_t As[2][64 * 64];
    __shared__ bf16_t Bs[2][128 * 64];

    // XCD swizzle: each XCD owns 3 N-tiles x all 26 M-tiles (624 = 8*26*3)
    const int lin = blockIdx.y * 24 + blockIdx.x;
    const int xcd = lin & 7, idx = lin >> 3;        // idx 0..77
    const int m0 = (idx / 3) * 64;
    const int n0 = (xcd * 3 + idx % 3) * 128;

    const int tid = threadIdx.x;
    const int w = tid >> 6, l = tid & 63, lr = l & 15, lg = l >> 4;
    const int wr = (w >> 1) * 32, wc = (w & 1) * 64;

    f32x4 acc[2][4] = {};

    auto stage = [&](int buf, int kt) {
        const int k0 = kt * 64, sg = k0 >> 10, kin = k0 & 1023;
        const bf16_t* Aseg = (sg == 1) ? xl : xh;
        const bf16_t* Bseg = (sg == 2) ? wql : wqh;
        stage64<64>(Aseg, m0, 1024, kin, As[buf], tid);
        stage64<128>(Bseg, n0, 1024, kin, Bs[buf], tid);
    };

    stage(0, 0);
    __syncthreads();
    int cur = 0;
    for (int kt = 0; kt < KX / 64; ++kt) {
        if (kt + 1 < KX / 64) stage(cur ^ 1, kt + 1);   // prefetch next tile
#pragma unroll
        for (int ks = 0; ks < 2; ++ks) {
            bf16x8 a[2];
#pragma unroll
            for (int rt = 0; rt < 2; ++rt) a[rt] = frag(As[cur], wr + 16 * rt + lr, ks * 4 + lg);
#pragma unroll
            for (int ct = 0; ct < 4; ++ct) {
                bf16x8 b = frag(Bs[cur], wc + 16 * ct + lr, ks * 4 + lg);
#pragma unroll
                for (int rt = 0; rt < 2; ++rt)
                    acc[rt][ct] = MFMA(a[rt], b, acc[rt][ct]);
            }
        }
        __syncthreads();   // drains prefetch (vmcnt) + protects cur for restage
        cur ^= 1;
    }

    // ---- epilogue: RoPE + split + head-major scatter ----
    const int which = n0 >> 10;               // 0=Q 1=K 2=V
    const int cbase = (n0 & 1023) + wc;       // wave's 64-col span = one head
    const float qscale = (which == 0) ? 0.125f : 1.0f;
    const float* sinp = rope;
    const float* cosp = rope + (size_t)HWIN * DH;

#pragma unroll
    for (int ct = 0; ct < 4; ++ct) {
        const int col = cbase + 16 * ct + lr;
        const int hd = col >> 6, dd = col & 63;
#pragma unroll
        for (int rt = 0; rt < 2; ++rt) {
            const int sbase = m0 + wr + 16 * rt + 4 * lg;   // + reg
            if (sbase >= NSEQ) continue;
            if (which == 2) {
                size_t off = ((size_t)hd * DH + dd) * NSEQP + sbase;
                if (sbase + 3 < NSEQ) {
                    BU t0, t1, t2, t3;
                    t0.b = (bf16_t)acc[rt][ct][0]; t1.b = (bf16_t)acc[rt][ct][1];
                    t2.b = (bf16_t)acc[rt][ct][2]; t3.b = (bf16_t)acc[rt][ct][3];
                    *(ushort4*)((u16*)Vt + off) = make_ushort4(t0.u, t1.u, t2.u, t3.u);
                } else {
#pragma unroll
                    for (int reg = 0; reg < 4; ++reg)
                        if (sbase + reg < NSEQ)
                            Vt[off + reg] = (bf16_t)acc[rt][ct][reg];
                }
            } else {
#pragma unroll
                for (int reg = 0; reg < 4; ++reg) {
                    const int seq = sbase + reg;
                    if (seq >= NSEQ) continue;
                    float val = acc[rt][ct][reg] * qscale;
                    float o = val;
                    if (seq >= PREFIX) {
                        float partner = acc[rt][ct ^ 2][reg] * qscale;
                        float rot = (dd < 32) ? -partner : partner;
                        float sn = sinp[(size_t)(seq - PREFIX) * DH + dd];
                        float cs = cosp[(size_t)(seq - PREFIX) * DH + dd];
                        o = val * cs + rot * sn;
                    }
                    bf16_t hh = (bf16_t)o;
                    bf16_t ll = (bf16_t)(o - (float)hh);
                    size_t off = ((size_t)hd * NSEQP + seq) * DH + dd;
                    if (which == 0) { Qhi[off] = hh; Qlo[off] = ll; }
                    else            { Khi[off] = hh; Klo[off] = ll; }
                }
            }
        }
    }
}

// ---------------------------------------------------------------------------
// Flash attention: block = (head, 64-q tile), 4 waves of 16 q rows.
// K_hi + V^T double-buffered in LDS (DMA staging); K_lo read DIRECT from
// global into registers (L2-resident, latency hidden under MFMA cluster).
// LDS 41984 B -> 3 blocks/CU. One barrier per tile; NSEQ mask on last
// tile only. O emitted as hi/lo bf16.
// ---------------------------------------------------------------------------
#define ASTRH 72
#define NJT   (NSEQP / 64)   // 26

__global__ __launch_bounds__(256, 3) void attn_kernel(
    const bf16_t* __restrict__ Qhi, const bf16_t* __restrict__ Qlo,
    const bf16_t* __restrict__ Khi, const bf16_t* __restrict__ Klo,
    const bf16_t* __restrict__ Vt,
    bf16_t* __restrict__ Oh, bf16_t* __restrict__ Ol)
{
    __shared__ bf16_t Ksh[2][64 * 64], Vsh[2][64 * 64];
    __shared__ bf16_t PS[4][16 * ASTRH];

    // XCD swizzle: 2 heads per XCD (416 = 8*2*26) -> K/V L2-resident
    const int lin = blockIdx.y * 26 + blockIdx.x;
    const int xcd = lin & 7, idx = lin >> 3;        // idx 0..51
    const int h = 2 * xcd + idx / 26;
    const int q0 = (idx % 26) * 64;

    const int tid = threadIdx.x, w = tid >> 6, l = tid & 63;
    const int lr = l & 15, lg = l >> 4;

    bf16x8 qh[2], ql[2];
    {
        const size_t qoff = ((size_t)h * NSEQP + q0 + 16 * w + lr) * DH;
#pragma unroll
        for (int ks = 0; ks < 2; ++ks) {
            qh[ks] = *(const bf16x8*)&Qhi[qoff + 32 * ks + 8 * lg];
            ql[ks] = *(const bf16x8*)&Qlo[qoff + 32 * ks + 8 * lg];
        }
    }

    const bf16_t* KbH = Khi + (size_t)h * NSEQP * DH;
    const bf16_t* KbL = Klo + (size_t)h * NSEQP * DH;
    const bf16_t* Vb  = Vt  + (size_t)h * DH * NSEQP;

    f32x4 o[4] = {};
    float m[4], lsum[4];
#pragma unroll
    for (int r = 0; r < 4; ++r) { m[r] = -1e30f; lsum[r] = 0.f; }

    auto stage_kv = [&](int buf, int jt) {
        const int j0 = jt * 64;
        stage64<64>(KbH, j0, 64, 0, Ksh[buf], tid);
        stage64<64>(Vb, 0, NSEQP, j0, Vsh[buf], tid);
    };

    stage_kv(0, 0);
    __syncthreads();
    int cur = 0;
    for (int jt = 0; jt < NJT; ++jt) {
        const int j0 = jt * 64;
        if (jt + 1 < NJT) stage_kv(cur ^ 1, jt + 1);   // prefetch next tile

        // K_lo fragments direct from global (issued early, L2-served)
        bf16x8 bl[4][2];
#pragma unroll
        for (int ct = 0; ct < 4; ++ct) {
            const size_t krow = (size_t)(j0 + 16 * ct + lr) * DH;
#pragma unroll
            for (int ks = 0; ks < 2; ++ks)
                bl[ct][ks] = *(const bf16x8*)&KbL[krow + 32 * ks + 8 * lg];
        }

        // ---- QK^T (split-3) ----
        f32x4 s[4] = {};
        __builtin_amdgcn_s_setprio(1);
#pragma unroll
        for (int ct = 0; ct < 4; ++ct) {
#pragma unroll
            for (int ks = 0; ks < 2; ++ks) {
                bf16x8 bh = frag(Ksh[cur], 16 * ct + lr, ks * 4 + lg);
                s[ct] = MFMA(ql[ks], bh, s[ct]);
                s[ct] = MFMA(qh[ks], bl[ct][ks], s[ct]);
                s[ct] = MFMA(qh[ks], bh, s[ct]);
            }
        }
        __builtin_amdgcn_s_setprio(0);

        if (jt == NJT - 1) {   // only the last tile straddles NSEQ
#pragma unroll
            for (int ct = 0; ct < 4; ++ct) {
                if (j0 + 16 * ct + lr >= NSEQ) {
                    s[ct][0] = -1e30f; s[ct][1] = -1e30f;
                    s[ct][2] = -1e30f; s[ct][3] = -1e30f;
                }
            }
        }

        // ---- online softmax ----
        float so[4];
#pragma unroll
        for (int reg = 0; reg < 4; ++reg) {
            float mt = fmaxf(fmaxf(s[0][reg], s[1][reg]), fmaxf(s[2][reg], s[3][reg]));
#pragma unroll
            for (int off = 1; off < 16; off <<= 1)
                mt = fmaxf(mt, __shfl_xor(mt, off));
            float mn = fmaxf(m[reg], mt);
            so[reg] = __expf(m[reg] - mn);
            m[reg] = mn;
            float psum = 0.f;
#pragma unroll
            for (int ct = 0; ct < 4; ++ct) {
                float pv = __expf(s[ct][reg] - mn);
                s[ct][reg] = pv;
                psum += pv;
            }
#pragma unroll
            for (int off = 1; off < 16; off <<= 1)
                psum += __shfl_xor(psum, off);
            lsum[reg] = lsum[reg] * so[reg] + psum;
        }

        // write P (wave-private rows; in-wave RAW ordered by lgkmcnt)
#pragma unroll
        for (int ct = 0; ct < 4; ++ct)
#pragma unroll
            for (int reg = 0; reg < 4; ++reg)
                PS[w][(4 * lg + reg) * ASTRH + 16 * ct + lr] = (bf16_t)s[ct][reg];

#pragma unroll
        for (int ctd = 0; ctd < 4; ++ctd)
#pragma unroll
            for (int reg = 0; reg < 4; ++reg)
                o[ctd][reg] *= so[reg];

        // ---- PV ----
        __builtin_amdgcn_s_setprio(1);
#pragma unroll
        for (int ks = 0; ks < 2; ++ks) {
            bf16x8 pa = *(const bf16x8*)&PS[w][lr * ASTRH + 32 * ks + 8 * lg];
#pragma unroll
            for (int ctd = 0; ctd < 4; ++ctd) {
                bf16x8 vb = frag(Vsh[cur], 16 * ctd + lr, ks * 4 + lg);
                o[ctd] = MFMA(pa, vb, o[ctd]);
            }
        }
        __builtin_amdgcn_s_setprio(0);

        __syncthreads();   // drains prefetch + protects cur before restage
        cur ^= 1;
    }

    // ---- epilogue: O -> hi/lo bf16 [seq][DIM] ----
#pragma unroll
    for (int ctd = 0; ctd < 4; ++ctd) {
#pragma unroll
        for (int reg = 0; reg < 4; ++reg) {
            const int seq = q0 + 16 * w + 4 * lg + reg;
            if (seq < NSEQ) {
                float ov = o[ctd][reg] / lsum[reg];
                bf16_t hi = (bf16_t)ov;
                bf16_t lo = (bf16_t)(ov - (float)hi);
                size_t oo = (size_t)seq * DIM + h * DH + 16 * ctd + lr;
                Oh[oo] = hi; Ol[oo] = lo;
            }
        }
    }
}

// ---------------------------------------------------------------------------
// GEMM 2: out = O @ W_proj^T + b over K'=3072. 64x64 tile, BK=64, 4 waves
// (2x2 of 32x32), 2-phase double-buffered. Grid 16x26 = 416.
// ---------------------------------------------------------------------------
__global__ __launch_bounds__(256, 2) void gemm_proj(
    const bf16_t* __restrict__ oh, const bf16_t* __restrict__ ol,
    const bf16_t* __restrict__ wph, const bf16_t* __restrict__ wpl,
    const float* __restrict__ bias, float* __restrict__ C)
{
    __shared__ bf16_t As[2][64 * 64];
    __shared__ bf16_t Bs[2][64 * 64];

    // XCD swizzle: 2 N-tiles per XCD x all 26 M (416 = 8*26*2)
    const int lin = blockIdx.y * 16 + blockIdx.x;
    const int xcd = lin & 7, idx = lin >> 3;        // idx 0..51
    const int m0 = (idx >> 1) * 64;
    const int n0 = ((xcd << 1) | (idx & 1)) * 64;

    const int tid = threadIdx.x;
    const int w = tid >> 6, l = tid & 63, lr = l & 15, lg = l >> 4;
    const int wr = (w >> 1) * 32, wc = (w & 1) * 32;

    f32x4 acc[2][2] = {};

    auto stage = [&](int buf, int kt) {
        const int k0 = kt * 64, sg = k0 >> 10, kin = k0 & 1023;
        const bf16_t* Aseg = (sg == 1) ? ol : oh;
        const bf16_t* Bseg = (sg == 2) ? wpl : wph;
        stage64<64>(Aseg, m0, 1024, kin, As[buf], tid);
        stage64<64>(Bseg, n0, 1024, kin, Bs[buf], tid);
    };

    stage(0, 0);
    __syncthreads();
    int cur = 0;
    for (int kt = 0; kt < KX / 64; ++kt) {
        if (kt + 1 < KX / 64) stage(cur ^ 1, kt + 1);
#pragma unroll
        for (int ks = 0; ks < 2; ++ks) {
            bf16x8 a[2];
#pragma unroll
            for (int rt = 0; rt < 2; ++rt) a[rt] = frag(As[cur], wr + 16 * rt + lr, ks * 4 + lg);
#pragma unroll
            for (int ct = 0; ct < 2; ++ct) {
                bf16x8 b = frag(Bs[cur], wc + 16 * ct + lr, ks * 4 + lg);
#pragma unroll
                for (int rt = 0; rt < 2; ++rt)
                    acc[rt][ct] = MFMA(a[rt], b, acc[rt][ct]);
            }
        }
        __syncthreads();
        cur ^= 1;
    }

#pragma unroll
    for (int ct = 0; ct < 2; ++ct) {
        const int n = n0 + wc + 16 * ct + lr;
        const float bv = bias[n];
#pragma unroll
        for (int rt = 0; rt < 2; ++rt) {
#pragma unroll
            for (int reg = 0; reg < 4; ++reg) {
                const int seq = m0 + wr + 16 * rt + 4 * lg + reg;
                if (seq < NSEQ)
                    C[(size_t)seq * DIM + n] = acc[rt][ct][reg] + bv;
            }
        }
    }
}

// ===========================================================================
extern "C" void kernel_launch(void* const* d_in, const int* in_sizes, int n_in,
                              void* d_out, int out_size, void* d_ws, size_t ws_size,
                              hipStream_t stream)
{
    const float* x     = (const float*)d_in[0];
    const float* rope  = (const float*)d_in[1];
    const float* Wqkv  = (const float*)d_in[2];
    const float* Wproj = (const float*)d_in[3];
    const float* bproj = (const float*)d_in[4];
    float* out = (float*)d_out;

    const size_t XE  = (size_t)NSEQP * 1024;
    const size_t WQE = (size_t)3072 * 1024;
    const size_t WPE = (size_t)1024 * 1024;
    const size_t HSE = (size_t)NH * NSEQP * DH;

    bf16_t* p = (bf16_t*)d_ws;
    bf16_t* xh  = p; p += XE;
    bf16_t* xl  = p; p += XE;
    bf16_t* wqh = p; p += WQE;
    bf16_t* wql = p; p += WQE;
    bf16_t* wph = p; p += WPE;
    bf16_t* wpl = p; p += WPE;
    bf16_t* Qhi = p; p += HSE;
    bf16_t* Qlo = p; p += HSE;
    bf16_t* Khi = p; p += HSE;
    bf16_t* Klo = p; p += HSE;
    bf16_t* Vt  = p; p += HSE;
    bf16_t* Oh  = xh;     // alias: x consumed by gemm_qkv before attn runs
    bf16_t* Ol  = xl;

    const int PTOT = NX4 + NQ4 + NP4;
    prep_kernel<<<(PTOT + 255) / 256, 256, 0, stream>>>(
        x, Wqkv, Wproj, xh, xl, wqh, wql, wph, wpl);

    gemm_qkv<<<dim3(24, NSEQP / 64), 256, 0, stream>>>(
        xh, xl, wqh, wql, rope, Qhi, Qlo, Khi, Klo, Vt);

    attn_kernel<<<dim3(26, NH), 256, 0, stream>>>(
        Qhi, Qlo, Khi, Klo, Vt, Oh, Ol);

    gemm_proj<<<dim3(16, NSEQP / 64), 256, 0, stream>>>(
        Oh, Ol, wph, wpl, bproj, out);
}

// Round 11
// 228.857 us; speedup vs baseline: 1.0389x; 1.0389x over previous
//
#include <hip/hip_runtime.h>
#include <hip/hip_bf16.h>

#define DIM    1024
#define NH     16
#define DH     64
#define NSEQ   1605
#define HWIN   1600
#define PREFIX 5
#define NSEQP  1664   // 26*64, padded M / padded seq
#define KX     3072   // extended K': split-3 as [hi | lo*Bh | hi*Bl] segments

typedef __bf16 bf16_t;
typedef bf16_t bf16x4 __attribute__((ext_vector_type(4)));
typedef bf16_t bf16x8 __attribute__((ext_vector_type(8)));
typedef float  f32x4  __attribute__((ext_vector_type(4)));
typedef unsigned short u16;

#define MFMA(a,b,c) __builtin_amdgcn_mfma_f32_16x16x32_bf16(a,b,c,0,0,0)

union BU { bf16_t b; u16 u; };

// ---------------------------------------------------------------------------
// global->LDS staging of [ROWS][64-half] tile: linear LDS dest, XOR chunk
// swizzle applied to the GLOBAL source, swizzled read via frag() below.
// ---------------------------------------------------------------------------
template<int ROWS>
__device__ __forceinline__ void stage64(const bf16_t* __restrict__ seg,
                                        int row0, int ldk, int kin,
                                        bf16_t* lds, int tid)
{
    const int l = tid & 63, w = tid >> 6;
#pragma unroll
    for (int i = 0; i < ROWS / 32; ++i) {
        const int rb = i * 32 + w * 8;            // wave-uniform LDS row base
        const int r  = rb + (l >> 3);             // lane's tile row
        const int p  = l & 7;                     // physical 16B chunk
        const bf16_t* src = seg + (size_t)(row0 + r) * ldk + kin + ((p ^ (r & 7)) << 3);
        __builtin_amdgcn_global_load_lds(
            (const __attribute__((address_space(1))) void*)src,
            (__attribute__((address_space(3))) void*)(lds + rb * 64),
            16, 0, 0);
    }
}

__device__ __forceinline__ bf16x8 frag(const bf16_t* lds, int row, int ch) {
    return *(const bf16x8*)&lds[row * 64 + ((ch ^ (row & 7)) << 3)];
}

// ---------------------------------------------------------------------------
// prep: split fp32 inputs into hi/lo bf16 planes.
// ---------------------------------------------------------------------------
#define NX4 (NSEQP * 256)
#define NQ4 (3072 * 256)
#define NP4 (1024 * 256)

__global__ __launch_bounds__(256) void prep_kernel(
    const float* __restrict__ x, const float* __restrict__ Wq,
    const float* __restrict__ Wp,
    bf16_t* __restrict__ xh, bf16_t* __restrict__ xl,
    bf16_t* __restrict__ wqh, bf16_t* __restrict__ wql,
    bf16_t* __restrict__ wph, bf16_t* __restrict__ wpl)
{
    const int i = blockIdx.x * 256 + threadIdx.x;
    if (i >= NX4 + NQ4 + NP4) return;
    float4 v = make_float4(0.f, 0.f, 0.f, 0.f);
    bf16_t *ph, *pl;
    size_t off;
    if (i < NX4) {
        if ((i >> 8) < NSEQ) v = ((const float4*)x)[i];
        ph = xh; pl = xl; off = (size_t)i * 4;
    } else if (i < NX4 + NQ4) {
        int j = i - NX4;
        v = ((const float4*)Wq)[j];
        ph = wqh; pl = wql; off = (size_t)j * 4;
    } else {
        int j = i - NX4 - NQ4;
        v = ((const float4*)Wp)[j];
        ph = wph; pl = wpl; off = (size_t)j * 4;
    }
    bf16_t h0 = (bf16_t)v.x, h1 = (bf16_t)v.y, h2 = (bf16_t)v.z, h3 = (bf16_t)v.w;
    bf16x4 hv = {h0, h1, h2, h3};
    bf16x4 lv = {(bf16_t)(v.x - (float)h0), (bf16_t)(v.y - (float)h1),
                 (bf16_t)(v.z - (float)h2), (bf16_t)(v.w - (float)h3)};
    *(bf16x4*)(ph + off) = hv;
    *(bf16x4*)(pl + off) = lv;
}

// ---------------------------------------------------------------------------
// GEMM 1: qkv = x @ W_qkv^T, plain bf16 GEMM over K'=3072.
// 64x128 tile, BK=64, 4 waves (2x2 of 32x64), 2-phase double-buffered LDS.
// Grid 24x26 = 624; XCD column-band swizzle. RoPE/split/V^T fused epilogue.
// ---------------------------------------------------------------------------
__global__ __launch_bounds__(256, 2) void gemm_qkv(
    const bf16_t* __restrict__ xh, const bf16_t* __restrict__ xl,
    const bf16_t* __restrict__ wqh, const bf16_t* __restrict__ wql,
    const float* __restrict__ rope,
    bf16_t* __restrict__ Qhi, bf16_t* __restrict__ Qlo,
    bf16_t* __restrict__ Khi, bf16_t* __restrict__ Klo,
    bf16_t* __restrict__ Vt)
{
    __shared__ bf16_t As[2][64 * 64];
    __shared__ bf16_t Bs[2][128 * 64];

    // XCD swizzle: each XCD owns 3 N-tiles x all 26 M-tiles (624 = 8*26*3)
    const int lin = blockIdx.y * 24 + blockIdx.x;
    const int xcd = lin & 7, idx = lin >> 3;        // idx 0..77
    const int m0 = (idx / 3) * 64;
    const int n0 = (xcd * 3 + idx % 3) * 128;

    const int tid = threadIdx.x;
    const int w = tid >> 6, l = tid & 63, lr = l & 15, lg = l >> 4;
    const int wr = (w >> 1) * 32, wc = (w & 1) * 64;

    f32x4 acc[2][4] = {};

    auto stage = [&](int buf, int kt) {
        const int k0 = kt * 64, sg = k0 >> 10, kin = k0 & 1023;
        const bf16_t* Aseg = (sg == 1) ? xl : xh;
        const bf16_t* Bseg = (sg == 2) ? wql : wqh;
        stage64<64>(Aseg, m0, 1024, kin, As[buf], tid);
        stage64<128>(Bseg, n0, 1024, kin, Bs[buf], tid);
    };

    stage(0, 0);
    __syncthreads();
    int cur = 0;
    for (int kt = 0; kt < KX / 64; ++kt) {
        if (kt + 1 < KX / 64) stage(cur ^ 1, kt + 1);   // prefetch next tile
#pragma unroll
        for (int ks = 0; ks < 2; ++ks) {
            bf16x8 a[2];
#pragma unroll
            for (int rt = 0; rt < 2; ++rt) a[rt] = frag(As[cur], wr + 16 * rt + lr, ks * 4 + lg);
#pragma unroll
            for (int ct = 0; ct < 4; ++ct) {
                bf16x8 b = frag(Bs[cur], wc + 16 * ct + lr, ks * 4 + lg);
#pragma unroll
                for (int rt = 0; rt < 2; ++rt)
                    acc[rt][ct] = MFMA(a[rt], b, acc[rt][ct]);
            }
        }
        __syncthreads();   // drains prefetch (vmcnt) + protects cur for restage
        cur ^= 1;
    }

    // ---- epilogue: RoPE + split + head-major scatter ----
    const int which = n0 >> 10;               // 0=Q 1=K 2=V
    const int cbase = (n0 & 1023) + wc;       // wave's 64-col span = one head
    const float qscale = (which == 0) ? 0.125f : 1.0f;
    const float* sinp = rope;
    const float* cosp = rope + (size_t)HWIN * DH;

#pragma unroll
    for (int ct = 0; ct < 4; ++ct) {
        const int col = cbase + 16 * ct + lr;
        const int hd = col >> 6, dd = col & 63;
#pragma unroll
        for (int rt = 0; rt < 2; ++rt) {
            const int sbase = m0 + wr + 16 * rt + 4 * lg;   // + reg
            if (sbase >= NSEQ) continue;
            if (which == 2) {
                size_t off = ((size_t)hd * DH + dd) * NSEQP + sbase;
                if (sbase + 3 < NSEQ) {
                    BU t0, t1, t2, t3;
                    t0.b = (bf16_t)acc[rt][ct][0]; t1.b = (bf16_t)acc[rt][ct][1];
                    t2.b = (bf16_t)acc[rt][ct][2]; t3.b = (bf16_t)acc[rt][ct][3];
                    *(ushort4*)((u16*)Vt + off) = make_ushort4(t0.u, t1.u, t2.u, t3.u);
                } else {
#pragma unroll
                    for (int reg = 0; reg < 4; ++reg)
                        if (sbase + reg < NSEQ)
                            Vt[off + reg] = (bf16_t)acc[rt][ct][reg];
                }
            } else {
#pragma unroll
                for (int reg = 0; reg < 4; ++reg) {
                    const int seq = sbase + reg;
                    if (seq >= NSEQ) continue;
                    float val = acc[rt][ct][reg] * qscale;
                    float o = val;
                    if (seq >= PREFIX) {
                        float partner = acc[rt][ct ^ 2][reg] * qscale;
                        float rot = (dd < 32) ? -partner : partner;
                        float sn = sinp[(size_t)(seq - PREFIX) * DH + dd];
                        float cs = cosp[(size_t)(seq - PREFIX) * DH + dd];
                        o = val * cs + rot * sn;
                    }
                    bf16_t hh = (bf16_t)o;
                    bf16_t ll = (bf16_t)(o - (float)hh);
                    size_t off = ((size_t)hd * NSEQP + seq) * DH + dd;
                    if (which == 0) { Qhi[off] = hh; Qlo[off] = ll; }
                    else            { Khi[off] = hh; Klo[off] = ll; }
                }
            }
        }
    }
}

// ---------------------------------------------------------------------------
// Flash attention with 2-way split-K over key tiles. Block = (head, 64-q
// tile, split). Split s handles key tiles [13s, 13s+13). Full-LDS staging
// (K hi/lo + V^T dbuf, DMA) - no per-tile dependent global reads. Emits
// UNNORMALIZED partial O (bf16) + per-row (m, l) fp32; merge_kernel combines.
// ---------------------------------------------------------------------------
#define ASTRH 72
#define NJT   (NSEQP / 64)   // 26
#define TPS   (NJT / 2)      // 13 tiles per split

__global__ __launch_bounds__(256, 2) void attn_kernel(
    const bf16_t* __restrict__ Qhi, const bf16_t* __restrict__ Qlo,
    const bf16_t* __restrict__ Khi, const bf16_t* __restrict__ Klo,
    const bf16_t* __restrict__ Vt,
    bf16_t* __restrict__ Opart, float* __restrict__ Oml)
{
    __shared__ bf16_t Ksh[2][64 * 64], Ksl[2][64 * 64], Vsh[2][64 * 64];
    __shared__ bf16_t PS[4][16 * ASTRH];

    // XCD swizzle on (x,y): 2 heads per XCD; z = key-split
    const int lin = blockIdx.y * 26 + blockIdx.x;
    const int xcd = lin & 7, idx = lin >> 3;        // idx 0..51
    const int h = 2 * xcd + idx / 26;
    const int q0 = (idx % 26) * 64;
    const int split = blockIdx.z;
    const int jt0 = split * TPS, jtend = jt0 + TPS;

    const int tid = threadIdx.x, w = tid >> 6, l = tid & 63;
    const int lr = l & 15, lg = l >> 4;

    bf16x8 qh[2], ql[2];
    {
        const size_t qoff = ((size_t)h * NSEQP + q0 + 16 * w + lr) * DH;
#pragma unroll
        for (int ks = 0; ks < 2; ++ks) {
            qh[ks] = *(const bf16x8*)&Qhi[qoff + 32 * ks + 8 * lg];
            ql[ks] = *(const bf16x8*)&Qlo[qoff + 32 * ks + 8 * lg];
        }
    }

    const bf16_t* KbH = Khi + (size_t)h * NSEQP * DH;
    const bf16_t* KbL = Klo + (size_t)h * NSEQP * DH;
    const bf16_t* Vb  = Vt  + (size_t)h * DH * NSEQP;

    f32x4 o[4] = {};
    float m[4], lsum[4];
#pragma unroll
    for (int r = 0; r < 4; ++r) { m[r] = -1e30f; lsum[r] = 0.f; }

    auto stage_kv = [&](int buf, int jt) {
        const int j0 = jt * 64;
        stage64<64>(KbH, j0, 64, 0, Ksh[buf], tid);
        stage64<64>(KbL, j0, 64, 0, Ksl[buf], tid);
        stage64<64>(Vb, 0, NSEQP, j0, Vsh[buf], tid);
    };

    stage_kv(0, jt0);
    __syncthreads();
    int cur = 0;
    for (int jt = jt0; jt < jtend; ++jt) {
        const int j0 = jt * 64;
        if (jt + 1 < jtend) stage_kv(cur ^ 1, jt + 1);   // prefetch next tile

        // ---- QK^T (split-3) ----
        f32x4 s[4] = {};
        __builtin_amdgcn_s_setprio(1);
#pragma unroll
        for (int ct = 0; ct < 4; ++ct) {
#pragma unroll
            for (int ks = 0; ks < 2; ++ks) {
                bf16x8 bh = frag(Ksh[cur], 16 * ct + lr, ks * 4 + lg);
                bf16x8 bl = frag(Ksl[cur], 16 * ct + lr, ks * 4 + lg);
                s[ct] = MFMA(ql[ks], bh, s[ct]);
                s[ct] = MFMA(qh[ks], bl, s[ct]);
                s[ct] = MFMA(qh[ks], bh, s[ct]);
            }
        }
        __builtin_amdgcn_s_setprio(0);

        if (jt == NJT - 1) {   // only the global last tile straddles NSEQ
#pragma unroll
            for (int ct = 0; ct < 4; ++ct) {
                if (j0 + 16 * ct + lr >= NSEQ) {
                    s[ct][0] = -1e30f; s[ct][1] = -1e30f;
                    s[ct][2] = -1e30f; s[ct][3] = -1e30f;
                }
            }
        }

        // ---- online softmax ----
        float so[4];
#pragma unroll
        for (int reg = 0; reg < 4; ++reg) {
            float mt = fmaxf(fmaxf(s[0][reg], s[1][reg]), fmaxf(s[2][reg], s[3][reg]));
#pragma unroll
            for (int off = 1; off < 16; off <<= 1)
                mt = fmaxf(mt, __shfl_xor(mt, off));
            float mn = fmaxf(m[reg], mt);
            so[reg] = __expf(m[reg] - mn);
            m[reg] = mn;
            float psum = 0.f;
#pragma unroll
            for (int ct = 0; ct < 4; ++ct) {
                float pv = __expf(s[ct][reg] - mn);
                s[ct][reg] = pv;
                psum += pv;
            }
#pragma unroll
            for (int off = 1; off < 16; off <<= 1)
                psum += __shfl_xor(psum, off);
            lsum[reg] = lsum[reg] * so[reg] + psum;
        }

        // write P (wave-private rows; in-wave RAW ordered by lgkmcnt)
#pragma unroll
        for (int ct = 0; ct < 4; ++ct)
#pragma unroll
            for (int reg = 0; reg < 4; ++reg)
                PS[w][(4 * lg + reg) * ASTRH + 16 * ct + lr] = (bf16_t)s[ct][reg];

#pragma unroll
        for (int ctd = 0; ctd < 4; ++ctd)
#pragma unroll
            for (int reg = 0; reg < 4; ++reg)
                o[ctd][reg] *= so[reg];

        // ---- PV ----
        __builtin_amdgcn_s_setprio(1);
#pragma unroll
        for (int ks = 0; ks < 2; ++ks) {
            bf16x8 pa = *(const bf16x8*)&PS[w][lr * ASTRH + 32 * ks + 8 * lg];
#pragma unroll
            for (int ctd = 0; ctd < 4; ++ctd) {
                bf16x8 vb = frag(Vsh[cur], 16 * ctd + lr, ks * 4 + lg);
                o[ctd] = MFMA(pa, vb, o[ctd]);
            }
        }
        __builtin_amdgcn_s_setprio(0);

        __syncthreads();   // drains prefetch + protects cur before restage
        cur ^= 1;
    }

    // ---- epilogue: unnormalized partial O (bf16) + (m,l) per row ----
    const size_t sb = ((size_t)split * NH + h) * NSEQP;
#pragma unroll
    for (int ctd = 0; ctd < 4; ++ctd) {
#pragma unroll
        for (int reg = 0; reg < 4; ++reg) {
            const int seq = q0 + 16 * w + 4 * lg + reg;
            if (seq < NSEQ)
                Opart[(sb + seq) * DH + 16 * ctd + lr] = (bf16_t)o[ctd][reg];
        }
    }
    if (lr == 0) {
#pragma unroll
        for (int reg = 0; reg < 4; ++reg) {
            const int seq = q0 + 16 * w + 4 * lg + reg;
            if (seq < NSEQ) {
                Oml[(sb + seq) * 2 + 0] = m[reg];
                Oml[(sb + seq) * 2 + 1] = lsum[reg];
            }
        }
    }
}

// ---------------------------------------------------------------------------
// merge: combine the two key-split partials -> O as hi/lo bf16 [seq][DIM].
// Grid (104, 16): block covers 16 q-rows x 64 dims.
// ---------------------------------------------------------------------------
__global__ __launch_bounds__(256) void merge_kernel(
    const bf16_t* __restrict__ Opart, const float* __restrict__ Oml,
    bf16_t* __restrict__ Oh, bf16_t* __restrict__ Ol)
{
    const int h = blockIdx.y;
    const int q = blockIdx.x * 16 + (threadIdx.x >> 4);
    const int d4 = (threadIdx.x & 15) * 4;
    if (q >= NSEQ) return;

    const size_t i0 = (size_t)h * NSEQP + q;
    const size_t i1 = ((size_t)NH + h) * NSEQP + q;
    const float m0 = Oml[i0 * 2], l0 = Oml[i0 * 2 + 1];
    const float m1 = Oml[i1 * 2], l1 = Oml[i1 * 2 + 1];
    const float M = fmaxf(m0, m1);
    const float a0 = __expf(m0 - M), a1 = __expf(m1 - M);
    const float inv = 1.0f / (l0 * a0 + l1 * a1);

    bf16x4 o0 = *(const bf16x4*)&Opart[i0 * DH + d4];
    bf16x4 o1 = *(const bf16x4*)&Opart[i1 * DH + d4];
    bf16x4 hv, lv;
#pragma unroll
    for (int j = 0; j < 4; ++j) {
        float v = (a0 * (float)o0[j] + a1 * (float)o1[j]) * inv;
        bf16_t hi = (bf16_t)v;
        hv[j] = hi;
        lv[j] = (bf16_t)(v - (float)hi);
    }
    const size_t oo = (size_t)q * DIM + h * DH + d4;
    *(bf16x4*)&Oh[oo] = hv;
    *(bf16x4*)&Ol[oo] = lv;
}

// ---------------------------------------------------------------------------
// GEMM 2: out = O @ W_proj^T + b over K'=3072. 64x64 tile, BK=64, 4 waves
// (2x2 of 32x32), 2-phase double-buffered. Grid 16x26 = 416.
// ---------------------------------------------------------------------------
__global__ __launch_bounds__(256, 2) void gemm_proj(
    const bf16_t* __restrict__ oh, const bf16_t* __restrict__ ol,
    const bf16_t* __restrict__ wph, const bf16_t* __restrict__ wpl,
    const float* __restrict__ bias, float* __restrict__ C)
{
    __shared__ bf16_t As[2][64 * 64];
    __shared__ bf16_t Bs[2][64 * 64];

    // XCD swizzle: 2 N-tiles per XCD x all 26 M (416 = 8*26*2)
    const int lin = blockIdx.y * 16 + blockIdx.x;
    const int xcd = lin & 7, idx = lin >> 3;        // idx 0..51
    const int m0 = (idx >> 1) * 64;
    const int n0 = ((xcd << 1) | (idx & 1)) * 64;

    const int tid = threadIdx.x;
    const int w = tid >> 6, l = tid & 63, lr = l & 15, lg = l >> 4;
    const int wr = (w >> 1) * 32, wc = (w & 1) * 32;

    f32x4 acc[2][2] = {};

    auto stage = [&](int buf, int kt) {
        const int k0 = kt * 64, sg = k0 >> 10, kin = k0 & 1023;
        const bf16_t* Aseg = (sg == 1) ? ol : oh;
        const bf16_t* Bseg = (sg == 2) ? wpl : wph;
        stage64<64>(Aseg, m0, 1024, kin, As[buf], tid);
        stage64<64>(Bseg, n0, 1024, kin, Bs[buf], tid);
    };

    stage(0, 0);
    __syncthreads();
    int cur = 0;
    for (int kt = 0; kt < KX / 64; ++kt) {
        if (kt + 1 < KX / 64) stage(cur ^ 1, kt + 1);
#pragma unroll
        for (int ks = 0; ks < 2; ++ks) {
            bf16x8 a[2];
#pragma unroll
            for (int rt = 0; rt < 2; ++rt) a[rt] = frag(As[cur], wr + 16 * rt + lr, ks * 4 + lg);
#pragma unroll
            for (int ct = 0; ct < 2; ++ct) {
                bf16x8 b = frag(Bs[cur], wc + 16 * ct + lr, ks * 4 + lg);
#pragma unroll
                for (int rt = 0; rt < 2; ++rt)
                    acc[rt][ct] = MFMA(a[rt], b, acc[rt][ct]);
            }
        }
        __syncthreads();
        cur ^= 1;
    }

#pragma unroll
    for (int ct = 0; ct < 2; ++ct) {
        const int n = n0 + wc + 16 * ct + lr;
        const float bv = bias[n];
#pragma unroll
        for (int rt = 0; rt < 2; ++rt) {
#pragma unroll
            for (int reg = 0; reg < 4; ++reg) {
                const int seq = m0 + wr + 16 * rt + 4 * lg + reg;
                if (seq < NSEQ)
                    C[(size_t)seq * DIM + n] = acc[rt][ct][reg] + bv;
            }
        }
    }
}

// ===========================================================================
extern "C" void kernel_launch(void* const* d_in, const int* in_sizes, int n_in,
                              void* d_out, int out_size, void* d_ws, size_t ws_size,
                              hipStream_t stream)
{
    const float* x     = (const float*)d_in[0];
    const float* rope  = (const float*)d_in[1];
    const float* Wqkv  = (const float*)d_in[2];
    const float* Wproj = (const float*)d_in[3];
    const float* bproj = (const float*)d_in[4];
    float* out = (float*)d_out;

    const size_t XE  = (size_t)NSEQP * 1024;
    const size_t WQE = (size_t)3072 * 1024;
    const size_t WPE = (size_t)1024 * 1024;
    const size_t HSE = (size_t)NH * NSEQP * DH;

    bf16_t* p = (bf16_t*)d_ws;
    bf16_t* xh  = p; p += XE;
    bf16_t* xl  = p; p += XE;
    bf16_t* wqh = p; p += WQE;
    bf16_t* wql = p; p += WQE;
    bf16_t* wph = p; p += WPE;
    bf16_t* wpl = p; p += WPE;
    bf16_t* Qhi = p; p += HSE;
    bf16_t* Qlo = p; p += HSE;
    bf16_t* Khi = p; p += HSE;
    bf16_t* Klo = p; p += HSE;
    bf16_t* Vt  = p; p += HSE;
    bf16_t* Opart = p; p += 2 * HSE;              // [split][h][q][64] bf16
    float*  Oml   = (float*)p;                    // [split][h][q][2] fp32
    bf16_t* Oh  = xh;     // alias: x consumed by gemm_qkv before merge runs
    bf16_t* Ol  = xl;

    const int PTOT = NX4 + NQ4 + NP4;
    prep_kernel<<<(PTOT + 255) / 256, 256, 0, stream>>>(
        x, Wqkv, Wproj, xh, xl, wqh, wql, wph, wpl);

    gemm_qkv<<<dim3(24, NSEQP / 64), 256, 0, stream>>>(
        xh, xl, wqh, wql, rope, Qhi, Qlo, Khi, Klo, Vt);

    attn_kernel<<<dim3(26, NH, 2), 256, 0, stream>>>(
        Qhi, Qlo, Khi, Klo, Vt, Opart, Oml);

    merge_kernel<<<dim3(NSEQP / 16, NH), 256, 0, stream>>>(
        Opart, Oml, Oh, Ol);

    gemm_proj<<<dim3(16, NSEQP / 64), 256, 0, stream>>>(
        Oh, Ol, wph, wpl, bproj, out);
}